// Round 1
// baseline (8720.757 us; speedup 1.0000x reference)
//
#include <hip/hip_runtime.h>
#include <stdint.h>

#define DEVI __device__ __forceinline__

typedef __attribute__((ext_vector_type(4))) float f32x4;
typedef __attribute__((ext_vector_type(8))) short bf16x8;

constexpr int NB = 64;      // batch
constexpr int NS = 512;     // seq
constexpr int NI = 1024;    // input size
constexpr int NH = 1024;    // hidden size
constexpr int NG = 4096;    // 4*H
constexpr int GBLK = 128;   // scan blocks (8 hidden units each)

DEVI unsigned short f2bf(float f) {
    unsigned u = __float_as_uint(f);
    unsigned r = (u + 0x7FFFu + ((u >> 16) & 1u)) >> 16;
    return (unsigned short)r;
}
DEVI float bf2f(unsigned short u) { return __uint_as_float(((unsigned)u) << 16); }

DEVI void gload_lds16(const void* g, void* l) {
    __builtin_amdgcn_global_load_lds(
        (const __attribute__((address_space(1))) unsigned int*)g,
        (__attribute__((address_space(3))) unsigned int*)l,
        16, 0, 0);
}

DEVI float fsigm(float x) { return 1.0f / (1.0f + __expf(-x)); }
DEVI float ftanh(float x) {
    x = fminf(fmaxf(x, -15.f), 15.f);
    float e = __expf(2.f * x);
    return (e - 1.f) / (e + 1.f);
}

#define MFMA16(a, b, c) __builtin_amdgcn_mfma_f32_16x16x32_bf16(a, b, c, 0, 0, 0)

// ---------------------------------------------------------------------------
// x[b][s][i] (f32) -> xT[s*64+b][i] (bf16)
__global__ void k_cast_x(const float* __restrict__ x, unsigned short* __restrict__ xT) {
    size_t e = ((size_t)blockIdx.x * blockDim.x + threadIdx.x) * 8;
    if (e >= (size_t)NB * NS * NI) return;
    unsigned i = (unsigned)(e & (NI - 1));
    unsigned s = (unsigned)((e >> 10) & (NS - 1));
    unsigned b = (unsigned)(e >> 19);
    const float4* p = (const float4*)(x + e);
    float4 v0 = p[0], v1 = p[1];
    bf16x8 w;
    w[0] = (short)f2bf(v0.x); w[1] = (short)f2bf(v0.y);
    w[2] = (short)f2bf(v0.z); w[3] = (short)f2bf(v0.w);
    w[4] = (short)f2bf(v1.x); w[5] = (short)f2bf(v1.y);
    w[6] = (short)f2bf(v1.z); w[7] = (short)f2bf(v1.w);
    *(bf16x8*)(xT + ((size_t)s * 64 + b) * NI + i) = w;
}

// src[rows][cols] (f32) -> dst[cols][rows] (bf16)
__global__ void k_transpose_cast(const float* __restrict__ src, unsigned short* __restrict__ dst,
                                 int rows, int cols) {
    __shared__ float tile[32][33];
    int c0 = blockIdx.x * 32;
    int r0 = blockIdx.y * 32;
    int tx = threadIdx.x & 31, ty = threadIdx.x >> 5;
    for (int rr = ty; rr < 32; rr += 8)
        tile[rr][tx] = src[(size_t)(r0 + rr) * cols + c0 + tx];
    __syncthreads();
    for (int rr = ty; rr < 32; rr += 8)
        dst[(size_t)(c0 + rr) * rows + r0 + tx] = f2bf(tile[tx][rr]);
}

// zero h double-buffer + barrier counter
__global__ void k_prep(unsigned* bar, uint4* hbufs) {
    size_t idx = (size_t)blockIdx.x * blockDim.x + threadIdx.x;
    if (idx < (size_t)2 * NB * NH * 2 / 16) hbufs[idx] = make_uint4(0, 0, 0, 0);
    if (idx == 0) *bar = 0;
}

// ---------------------------------------------------------------------------
// xW[s*64+b][g] = xT row . WT col + bias   (m97-structure 128x128x32 bf16 MFMA)
template <int XW_F32>
__global__ __launch_bounds__(256) void k_gemm_xw(
    const unsigned short* __restrict__ xT,   // [32768][1024]
    const unsigned short* __restrict__ WT,   // [4096][1024]  (= W^T)
    const float* __restrict__ bias,
    void* __restrict__ xw_out) {
    __shared__ unsigned short smA[128 * 32];
    __shared__ unsigned short smB[128 * 32];
    const int tid = threadIdx.x;
    const int w = tid >> 6, lane = tid & 63;
    const int l15 = lane & 15, l4 = lane >> 4;
    const int tm = blockIdx.x >> 5;   // 256 M tiles
    const int tn = blockIdx.x & 31;   // 32 N tiles
    const int rowbase = tm * 128, colbase = tn * 128;

    f32x4 zero = {0.f, 0.f, 0.f, 0.f};
    f32x4 acc[4][4];
#pragma unroll
    for (int mt = 0; mt < 4; ++mt)
#pragma unroll
        for (int nt = 0; nt < 4; ++nt) acc[mt][nt] = zero;

    for (int kk = 0; kk < 32; ++kk) {
        __syncthreads();
#pragma unroll
        for (int q = 0; q < 2; ++q) {
            int instr = w * 2 + q;
            int Lidx = instr * 64 + lane;        // 0..511
            int row = Lidx >> 2;                 // 0..127
            int koff = (Lidx & 3) * 16;          // bytes in 64B row
            gload_lds16((const char*)xT + ((size_t)(rowbase + row)) * 2048 + kk * 64 + koff,
                        (char*)smA + instr * 1024);
            gload_lds16((const char*)WT + ((size_t)(colbase + row)) * 2048 + kk * 64 + koff,
                        (char*)smB + instr * 1024);
        }
        __syncthreads();
        bf16x8 a[4], b[4];
        int mb = (w & 1) * 64, nb = (w >> 1) * 64;
#pragma unroll
        for (int mt = 0; mt < 4; ++mt)
            a[mt] = *(const bf16x8*)((const char*)smA + (mb + mt * 16 + l15) * 64 + l4 * 16);
#pragma unroll
        for (int nt = 0; nt < 4; ++nt)
            b[nt] = *(const bf16x8*)((const char*)smB + (nb + nt * 16 + l15) * 64 + l4 * 16);
#pragma unroll
        for (int mt = 0; mt < 4; ++mt)
#pragma unroll
            for (int nt = 0; nt < 4; ++nt)
                acc[mt][nt] = MFMA16(a[mt], b[nt], acc[mt][nt]);
    }
    int mbase = rowbase + (w & 1) * 64, nbase = colbase + (w >> 1) * 64;
#pragma unroll
    for (int nt = 0; nt < 4; ++nt) {
        int col = nbase + nt * 16 + l15;
        float bv = bias[col];
#pragma unroll
        for (int mt = 0; mt < 4; ++mt)
#pragma unroll
            for (int r = 0; r < 4; ++r) {
                int row = mbase + mt * 16 + l4 * 4 + r;
                float v = acc[mt][nt][r] + bv;
                if (XW_F32)
                    ((float*)xw_out)[(size_t)row * NG + col] = v;
                else
                    ((unsigned short*)xw_out)[(size_t)row * NG + col] = f2bf(v);
            }
    }
}

// ---------------------------------------------------------------------------
// Persistent scan: 128 blocks x 256 thr; block owns hidden units [8*blk, 8*blk+8)
// (gate cols {q*1024 + j}). U-slice (32 cols x 1024) lives in LDS, XOR-swizzled.
template <int XW_F32>
__global__ __launch_bounds__(256) void k_scan(
    const unsigned short* __restrict__ UT,   // [4096][1024] (= U^T, bf16)
    const void* __restrict__ xw,             // [32768][4096]
    unsigned short* __restrict__ hbuf,       // [2][64][1024] bf16
    float* __restrict__ out,                 // hidden_seq | h_t | c_t
    unsigned* __restrict__ bar) {
    extern __shared__ char sm[];   // 64 KB U-slice
    const int tid = threadIdx.x, w = tid >> 6, lane = tid & 63;
    const int l15 = lane & 15, l4 = lane >> 4, jj = lane & 7;
    const int jbase = blockIdx.x * 8;

    // stage U-slice, swizzled: LDS(n, off) = UT(colg(n), off ^ ((n&7)<<4))
    for (int it = 0; it < 16; ++it) {
        int instr = it * 4 + w;
        int Lb = instr * 1024 + lane * 16;
        int n = Lb >> 11;                       // local col 0..31
        int off = Lb & 2047;
        int k2 = off ^ ((n & 7) << 4);
        int colg = (n >> 3) * 1024 + jbase + (n & 7);
        gload_lds16((const char*)UT + (size_t)colg * 2048 + k2, sm + instr * 1024);
    }
    __syncthreads();

    const int batch0 = w * 16;
    float c[4] = {0.f, 0.f, 0.f, 0.f};
    const int q0 = l15 >> 3;
    const int colg0 = q0 * 1024 + jbase + jj;          // gates i/f
    const int colg1 = (2 + q0) * 1024 + jbase + jj;    // gates g/o
    const size_t HOFF = (size_t)NB * NS * NH;          // 33554432
    const size_t COFF = HOFF + (size_t)NB * NH;

    for (int t = 0; t < NS; ++t) {
        const unsigned short* hp = hbuf + (size_t)(t & 1) * (NB * NH);
        unsigned short* hn = hbuf + (size_t)((t + 1) & 1) * (NB * NH);

        // seed accumulators with xw (C-in of MFMA)
        f32x4 acc0, acc1;
#pragma unroll
        for (int r = 0; r < 4; ++r) {
            int batch = batch0 + l4 * 4 + r;
            size_t rowoff = ((size_t)t * 64 + batch) * NG;
            if (XW_F32) {
                acc0[r] = ((const float*)xw)[rowoff + colg0];
                acc1[r] = ((const float*)xw)[rowoff + colg1];
            } else {
                acc0[r] = bf2f(((const unsigned short*)xw)[rowoff + colg0]);
                acc1[r] = bf2f(((const unsigned short*)xw)[rowoff + colg1]);
            }
        }

        // h @ U-slice : A rows = batches (row=lane&15), ring-prefetched agent loads
        const char* abase = (const char*)hp + (size_t)(batch0 + l15) * 2048 + l4 * 16;
        unsigned long long plo[8], phi[8];
#pragma unroll
        for (int kk = 0; kk < 8; ++kk) {
            plo[kk] = __hip_atomic_load((const unsigned long long*)(abase + kk * 64),
                                        __ATOMIC_RELAXED, __HIP_MEMORY_SCOPE_AGENT);
            phi[kk] = __hip_atomic_load((const unsigned long long*)(abase + kk * 64 + 8),
                                        __ATOMIC_RELAXED, __HIP_MEMORY_SCOPE_AGENT);
        }
#pragma unroll
        for (int kk = 0; kk < 32; ++kk) {
            union { unsigned long long q[2]; bf16x8 v; } u;
            u.q[0] = plo[kk & 7]; u.q[1] = phi[kk & 7];
            if (kk < 24) {
                plo[kk & 7] = __hip_atomic_load((const unsigned long long*)(abase + (kk + 8) * 64),
                                                __ATOMIC_RELAXED, __HIP_MEMORY_SCOPE_AGENT);
                phi[kk & 7] = __hip_atomic_load((const unsigned long long*)(abase + (kk + 8) * 64 + 8),
                                                __ATOMIC_RELAXED, __HIP_MEMORY_SCOPE_AGENT);
            }
            int k2 = kk * 64 + l4 * 16;
            bf16x8 b0 = *(const bf16x8*)(sm + (size_t)l15 * 2048 + (k2 ^ (jj << 4)));
            bf16x8 b1 = *(const bf16x8*)(sm + (size_t)(16 + l15) * 2048 + (k2 ^ (jj << 4)));
            acc0 = MFMA16(u.v, b0, acc0);
            acc1 = MFMA16(u.v, b1, acc1);
        }

        // elementwise: lanes l and l^8 pair up (i,f) / (g,o) for one hidden unit
#pragma unroll
        for (int r = 0; r < 4; ++r) {
            float p0 = acc0[r], p1 = acc1[r];
            float s0 = __shfl_xor(p0, 8);
            float s1 = __shfl_xor(p1, 8);
            bool hiLane = (lane & 8) != 0;
            float iv = hiLane ? s0 : p0;
            float fv = hiLane ? p0 : s0;
            float gv = hiLane ? s1 : p1;
            float ov = hiLane ? p1 : s1;
            float cn = fsigm(fv) * c[r] + fsigm(iv) * ftanh(gv);
            c[r] = cn;
            float h = fsigm(ov) * ftanh(cn);
            if (!hiLane) {
                int batch = batch0 + l4 * 4 + r;
                int j = jbase + jj;
                __hip_atomic_store(hn + (size_t)batch * NH + j, f2bf(h),
                                   __ATOMIC_RELAXED, __HIP_MEMORY_SCOPE_AGENT);
                out[((size_t)batch * NS + t) * NH + j] = h;
                if (t == NS - 1) {
                    out[HOFF + (size_t)batch * NH + j] = h;
                    out[COFF + (size_t)batch * NH + j] = cn;
                }
            }
        }

        // grid barrier: syncthreads drains vmcnt(0) -> h-stores visible at L3
        __syncthreads();
        if (tid == 0) {
            __hip_atomic_fetch_add(bar, 1u, __ATOMIC_ACQ_REL, __HIP_MEMORY_SCOPE_AGENT);
            unsigned target = (unsigned)(t + 1) * GBLK;
            while (__hip_atomic_load(bar, __ATOMIC_ACQUIRE, __HIP_MEMORY_SCOPE_AGENT) < target) {}
        }
        __syncthreads();
    }
}

// ---------------------------------------------------------------------------
extern "C" void kernel_launch(void* const* d_in, const int* in_sizes, int n_in,
                              void* d_out, int out_size, void* d_ws, size_t ws_size,
                              hipStream_t stream) {
    const float* x    = (const float*)d_in[0];
    const float* W    = (const float*)d_in[1];
    const float* U    = (const float*)d_in[2];
    const float* bias = (const float*)d_in[3];
    float* out = (float*)d_out;
    char* ws = (char*)d_ws;

    const size_t bar_off  = 0;
    const size_t hbuf_off = 256;
    const size_t xT_off   = hbuf_off + (size_t)2 * NB * NH * 2;        // 262400
    const size_t WT_off   = xT_off + (size_t)NS * NB * NI * 2;         // +64MB
    const size_t UT_off   = WT_off + (size_t)NG * NI * 2;              // +8MB
    const size_t xw_off   = UT_off + (size_t)NG * NI * 2;              // +8MB
    const size_t need_f32 = xw_off + (size_t)NS * NB * NG * 4;         // ~592MB
    const bool xwf32 = (ws_size >= need_f32);

    unsigned* bar        = (unsigned*)(ws + bar_off);
    unsigned short* hbuf = (unsigned short*)(ws + hbuf_off);
    unsigned short* xT   = (unsigned short*)(ws + xT_off);
    unsigned short* WT   = (unsigned short*)(ws + WT_off);
    unsigned short* UT   = (unsigned short*)(ws + UT_off);
    void* xw             = (void*)(ws + xw_off);

    k_cast_x<<<16384, 256, 0, stream>>>(x, xT);
    dim3 tg(NG / 32, NI / 32);
    k_transpose_cast<<<tg, 256, 0, stream>>>(W, WT, NI, NG);
    k_transpose_cast<<<tg, 256, 0, stream>>>(U, UT, NH, NG);
    k_prep<<<64, 256, 0, stream>>>(bar, (uint4*)hbuf);
    if (xwf32) {
        k_gemm_xw<1><<<(NS * NB / 128) * (NG / 128), 256, 0, stream>>>(xT, WT, bias, xw);
        k_scan<1><<<GBLK, 256, 65536, stream>>>(UT, xw, hbuf, out, bar);
    } else {
        k_gemm_xw<0><<<(NS * NB / 128) * (NG / 128), 256, 0, stream>>>(xT, WT, bias, xw);
        k_scan<0><<<GBLK, 256, 65536, stream>>>(UT, xw, hbuf, out, bar);
    }
}

// Round 3
// 8288.016 us; speedup vs baseline: 1.0522x; 1.0522x over previous
//
#include <hip/hip_runtime.h>
#include <stdint.h>

#define DEVI __device__ __forceinline__

typedef __attribute__((ext_vector_type(4))) float f32x4;
typedef __attribute__((ext_vector_type(8))) short bf16x8;

constexpr int NB = 64;      // batch
constexpr int NS = 512;     // seq
constexpr int NI = 1024;    // input size
constexpr int NH = 1024;    // hidden size
constexpr int NG = 4096;    // 4*H
constexpr int GBLK = 128;   // scan blocks (8 hidden units each)

DEVI unsigned short f2bf(float f) {
    unsigned u = __float_as_uint(f);
    unsigned r = (u + 0x7FFFu + ((u >> 16) & 1u)) >> 16;
    return (unsigned short)r;
}
DEVI float bf2f(unsigned short u) { return __uint_as_float(((unsigned)u) << 16); }

DEVI void gload_lds16(const void* g, void* l) {
    __builtin_amdgcn_global_load_lds(
        (const __attribute__((address_space(1))) unsigned int*)g,
        (__attribute__((address_space(3))) unsigned int*)l,
        16, 0, 0);
}

DEVI float fsigm(float x) { return 1.0f / (1.0f + __expf(-x)); }
DEVI float ftanh(float x) {
    x = fminf(fmaxf(x, -15.f), 15.f);
    float e = __expf(2.f * x);
    return (e - 1.f) / (e + 1.f);
}

#define MFMA16(a, b, c) __builtin_amdgcn_mfma_f32_16x16x32_bf16(a, b, c, 0, 0, 0)

// ---------------------------------------------------------------------------
// x[b][s][i] (f32) -> xT[s*64+b][i] (bf16)
__global__ void k_cast_x(const float* __restrict__ x, unsigned short* __restrict__ xT) {
    size_t e = ((size_t)blockIdx.x * blockDim.x + threadIdx.x) * 8;
    if (e >= (size_t)NB * NS * NI) return;
    unsigned i = (unsigned)(e & (NI - 1));
    unsigned s = (unsigned)((e >> 10) & (NS - 1));
    unsigned b = (unsigned)(e >> 19);
    const float4* p = (const float4*)(x + e);
    float4 v0 = p[0], v1 = p[1];
    bf16x8 w;
    w[0] = (short)f2bf(v0.x); w[1] = (short)f2bf(v0.y);
    w[2] = (short)f2bf(v0.z); w[3] = (short)f2bf(v0.w);
    w[4] = (short)f2bf(v1.x); w[5] = (short)f2bf(v1.y);
    w[6] = (short)f2bf(v1.z); w[7] = (short)f2bf(v1.w);
    *(bf16x8*)(xT + ((size_t)s * 64 + b) * NI + i) = w;
}

// src[rows][cols] (f32) -> dst[cols][rows] (bf16)
__global__ void k_transpose_cast(const float* __restrict__ src, unsigned short* __restrict__ dst,
                                 int rows, int cols) {
    __shared__ float tile[32][33];
    int c0 = blockIdx.x * 32;
    int r0 = blockIdx.y * 32;
    int tx = threadIdx.x & 31, ty = threadIdx.x >> 5;
    for (int rr = ty; rr < 32; rr += 8)
        tile[rr][tx] = src[(size_t)(r0 + rr) * cols + c0 + tx];
    __syncthreads();
    for (int rr = ty; rr < 32; rr += 8)
        dst[(size_t)(c0 + rr) * rows + r0 + tx] = f2bf(tile[tx][rr]);
}

// zero flags region + h double-buffer
__global__ void k_prep(uint4* ws0) {
    size_t idx = (size_t)blockIdx.x * blockDim.x + threadIdx.x;
    if (idx < (4096 + 2 * NB * NH * 2) / 16) ws0[idx] = make_uint4(0, 0, 0, 0);
}

// ---------------------------------------------------------------------------
// xW[s*64+b][g] = xT row . WT col + bias   (m97-structure 128x128x32 bf16 MFMA)
template <int XW_F32>
__global__ __launch_bounds__(256) void k_gemm_xw(
    const unsigned short* __restrict__ xT,   // [32768][1024]
    const unsigned short* __restrict__ WT,   // [4096][1024]  (= W^T)
    const float* __restrict__ bias,
    void* __restrict__ xw_out) {
    __shared__ unsigned short smA[128 * 32];
    __shared__ unsigned short smB[128 * 32];
    const int tid = threadIdx.x;
    const int w = tid >> 6, lane = tid & 63;
    const int l15 = lane & 15, l4 = lane >> 4;
    const int tm = blockIdx.x >> 5;   // 256 M tiles
    const int tn = blockIdx.x & 31;   // 32 N tiles
    const int rowbase = tm * 128, colbase = tn * 128;

    f32x4 zero = {0.f, 0.f, 0.f, 0.f};
    f32x4 acc[4][4];
#pragma unroll
    for (int mt = 0; mt < 4; ++mt)
#pragma unroll
        for (int nt = 0; nt < 4; ++nt) acc[mt][nt] = zero;

    for (int kk = 0; kk < 32; ++kk) {
        __syncthreads();
#pragma unroll
        for (int q = 0; q < 2; ++q) {
            int instr = w * 2 + q;
            int Lidx = instr * 64 + lane;        // 0..511
            int row = Lidx >> 2;                 // 0..127
            int koff = (Lidx & 3) * 16;          // bytes in 64B row
            gload_lds16((const char*)xT + ((size_t)(rowbase + row)) * 2048 + kk * 64 + koff,
                        (char*)smA + instr * 1024);
            gload_lds16((const char*)WT + ((size_t)(colbase + row)) * 2048 + kk * 64 + koff,
                        (char*)smB + instr * 1024);
        }
        __syncthreads();
        bf16x8 a[4], b[4];
        int mb = (w & 1) * 64, nb = (w >> 1) * 64;
#pragma unroll
        for (int mt = 0; mt < 4; ++mt)
            a[mt] = *(const bf16x8*)((const char*)smA + (mb + mt * 16 + l15) * 64 + l4 * 16);
#pragma unroll
        for (int nt = 0; nt < 4; ++nt)
            b[nt] = *(const bf16x8*)((const char*)smB + (nb + nt * 16 + l15) * 64 + l4 * 16);
#pragma unroll
        for (int mt = 0; mt < 4; ++mt)
#pragma unroll
            for (int nt = 0; nt < 4; ++nt)
                acc[mt][nt] = MFMA16(a[mt], b[nt], acc[mt][nt]);
    }
    int mbase = rowbase + (w & 1) * 64, nbase = colbase + (w >> 1) * 64;
#pragma unroll
    for (int nt = 0; nt < 4; ++nt) {
        int col = nbase + nt * 16 + l15;
        float bv = bias[col];
#pragma unroll
        for (int mt = 0; mt < 4; ++mt)
#pragma unroll
            for (int r = 0; r < 4; ++r) {
                int row = mbase + mt * 16 + l4 * 4 + r;
                float v = acc[mt][nt][r] + bv;
                if (XW_F32)
                    ((float*)xw_out)[(size_t)row * NG + col] = v;
                else
                    ((unsigned short*)xw_out)[(size_t)row * NG + col] = f2bf(v);
            }
    }
}

// ---------------------------------------------------------------------------
// Persistent scan: 128 blocks x 256 thr; block owns hidden units [8*blk, 8*blk+8).
// Flat store-flag barrier; h loads are plain dwordx4 after agent-acquire fence.
template <int XW_F32>
__global__ __launch_bounds__(256, 1) void k_scan(
    const unsigned short* __restrict__ UT,   // [4096][1024] (= U^T, bf16)
    const void* __restrict__ xw,             // [32768][4096]
    unsigned short* __restrict__ hbuf,       // [2][64][1024] bf16
    float* __restrict__ out,                 // hidden_seq | h_t | c_t
    unsigned* __restrict__ flags) {          // [GBLK]
    extern __shared__ char sm[];   // 64 KB U-slice
    const int tid = threadIdx.x, w = tid >> 6, lane = tid & 63;
    const int l15 = lane & 15, l4 = lane >> 4, jj = lane & 7;
    const int jbase = blockIdx.x * 8;

    // stage U-slice, swizzled: LDS(n, off) = UT(colg(n), off ^ ((n&7)<<4))
    for (int it = 0; it < 16; ++it) {
        int instr = it * 4 + w;
        int Lb = instr * 1024 + lane * 16;
        int n = Lb >> 11;                       // local col 0..31
        int off = Lb & 2047;
        int k2 = off ^ ((n & 7) << 4);
        int colg = (n >> 3) * 1024 + jbase + (n & 7);
        gload_lds16((const char*)UT + (size_t)colg * 2048 + k2, sm + instr * 1024);
    }
    __syncthreads();

    const int batch0 = w * 16;
    const int q0 = l15 >> 3;
    const int colg0 = q0 * 1024 + jbase + jj;          // gates i/f
    const int colg1 = (2 + q0) * 1024 + jbase + jj;    // gates g/o
    const size_t HOFF = (size_t)NB * NS * NH;
    const size_t COFF = HOFF + (size_t)NB * NH;

    float c[4] = {0.f, 0.f, 0.f, 0.f};
    float s0c[4], s1c[4];
    // preload seeds for t=0 (xw written by prior dispatch -> visible)
#pragma unroll
    for (int r = 0; r < 4; ++r) {
        int batch = batch0 + l4 * 4 + r;
        size_t rowoff = (size_t)batch * NG;
        if (XW_F32) {
            s0c[r] = ((const float*)xw)[rowoff + colg0];
            s1c[r] = ((const float*)xw)[rowoff + colg1];
        } else {
            s0c[r] = bf2f(((const unsigned short*)xw)[rowoff + colg0]);
            s1c[r] = bf2f(((const unsigned short*)xw)[rowoff + colg1]);
        }
    }

    for (int t = 0; t < NS; ++t) {
        const bool notLast = (t + 1 < NS);
        unsigned short* hn = hbuf + (size_t)((t + 1) & 1) * (NB * NH);

        f32x4 acc0, acc1;
#pragma unroll
        for (int r = 0; r < 4; ++r) { acc0[r] = s0c[r]; acc1[r] = s1c[r]; }

        // prefetch next step's xw seeds (independent of h; overlaps everything)
        float s0n[4], s1n[4];
        if (notLast) {
#pragma unroll
            for (int r = 0; r < 4; ++r) {
                int batch = batch0 + l4 * 4 + r;
                size_t rowoff = ((size_t)(t + 1) * 64 + batch) * NG;
                if (XW_F32) {
                    s0n[r] = ((const float*)xw)[rowoff + colg0];
                    s1n[r] = ((const float*)xw)[rowoff + colg1];
                } else {
                    s0n[r] = bf2f(((const unsigned short*)xw)[rowoff + colg0]);
                    s1n[r] = bf2f(((const unsigned short*)xw)[rowoff + colg1]);
                }
            }
        }

        // h fragments: plain vector loads (fresh after agent-acquire fence),
        // all 32 issued up-front -> full vmcnt-depth pipelining, L1/L2 reuse.
        const char* abase = (const char*)hbuf + (size_t)(t & 1) * (NB * NH * 2) +
                            (size_t)(batch0 + l15) * 2048 + l4 * 16;
        bf16x8 hf[32];
#pragma unroll
        for (int kk = 0; kk < 32; ++kk)
            hf[kk] = *(const bf16x8*)(abase + (size_t)kk * 64);

#pragma unroll
        for (int kk = 0; kk < 32; ++kk) {
            int k2 = kk * 64 + l4 * 16;
            bf16x8 b0 = *(const bf16x8*)(sm + (size_t)l15 * 2048 + (k2 ^ (jj << 4)));
            bf16x8 b1 = *(const bf16x8*)(sm + (size_t)(16 + l15) * 2048 + (k2 ^ (jj << 4)));
            acc0 = MFMA16(hf[kk], b0, acc0);
            acc1 = MFMA16(hf[kk], b1, acc1);
        }

        // elementwise: lanes l and l^8 pair up (i,f)/(g,o) for one hidden unit
        float hsv[4], csv[4];
#pragma unroll
        for (int r = 0; r < 4; ++r) {
            float p0 = acc0[r], p1 = acc1[r];
            float s0 = __shfl_xor(p0, 8);
            float s1 = __shfl_xor(p1, 8);
            bool hiLane = (lane & 8) != 0;
            float iv = hiLane ? s0 : p0;
            float fv = hiLane ? p0 : s0;
            float gv = hiLane ? s1 : p1;
            float ov = hiLane ? p1 : s1;
            float cn = fsigm(fv) * c[r] + fsigm(iv) * ftanh(gv);
            c[r] = cn;
            float h = fsigm(ov) * ftanh(cn);
            hsv[r] = h; csv[r] = cn;
            if (!hiLane) {
                int batch = batch0 + l4 * 4 + r;
                __hip_atomic_store(hn + (size_t)batch * NH + jbase + jj, f2bf(h),
                                   __ATOMIC_RELAXED, __HIP_MEMORY_SCOPE_AGENT);
            }
        }

        // drain h stores (all waves), then publish arrival flag
        asm volatile("s_waitcnt vmcnt(0)" ::: "memory");
        __syncthreads();
        if (notLast && tid == 0)
            __hip_atomic_store(flags + blockIdx.x, (unsigned)(t + 1),
                               __ATOMIC_RELEASE, __HIP_MEMORY_SCOPE_AGENT);

        // out stores AFTER the flag (off the critical path)
#pragma unroll
        for (int r = 0; r < 4; ++r) {
            if ((lane & 8) == 0) {
                int batch = batch0 + l4 * 4 + r;
                int j = jbase + jj;
                out[((size_t)batch * NS + t) * NH + j] = hsv[r];
                if (t == NS - 1) {
                    out[HOFF + (size_t)batch * NH + j] = hsv[r];
                    out[COFF + (size_t)batch * NH + j] = csv[r];
                }
            }
        }

        if (notLast) {
            // flat barrier wait: wave 0 polls all 128 flags as 64 x u64
            if (w == 0) {
                const unsigned target = (unsigned)(t + 1);
                const unsigned long long* fl = (const unsigned long long*)flags;
                bool ok;
                do {
                    unsigned long long v = __hip_atomic_load(fl + lane, __ATOMIC_RELAXED,
                                                             __HIP_MEMORY_SCOPE_AGENT);
                    ok = ((unsigned)v >= target) && ((unsigned)(v >> 32) >= target);
                } while (!__all(ok));
            }
            __syncthreads();
            __builtin_amdgcn_fence(__ATOMIC_ACQUIRE, "agent");  // invalidate stale h in L1/L2
#pragma unroll
            for (int r = 0; r < 4; ++r) { s0c[r] = s0n[r]; s1c[r] = s1n[r]; }
        }
    }
}

// ---------------------------------------------------------------------------
extern "C" void kernel_launch(void* const* d_in, const int* in_sizes, int n_in,
                              void* d_out, int out_size, void* d_ws, size_t ws_size,
                              hipStream_t stream) {
    const float* x    = (const float*)d_in[0];
    const float* W    = (const float*)d_in[1];
    const float* U    = (const float*)d_in[2];
    const float* bias = (const float*)d_in[3];
    float* out = (float*)d_out;
    char* ws = (char*)d_ws;

    const size_t flags_off = 0;                                       // 512B used, 4KB pad
    const size_t hbuf_off  = 4096;
    const size_t xT_off    = hbuf_off + (size_t)2 * NB * NH * 2;      // 266240
    const size_t WT_off    = xT_off + (size_t)NS * NB * NI * 2;       // +64MB
    const size_t UT_off    = WT_off + (size_t)NG * NI * 2;            // +8MB
    const size_t xw_off    = UT_off + (size_t)NG * NI * 2;            // +8MB
    const size_t need_f32  = xw_off + (size_t)NS * NB * NG * 4;       // ~592MB
    const bool xwf32 = (ws_size >= need_f32);

    unsigned* flags      = (unsigned*)(ws + flags_off);
    unsigned short* hbuf = (unsigned short*)(ws + hbuf_off);
    unsigned short* xT   = (unsigned short*)(ws + xT_off);
    unsigned short* WT   = (unsigned short*)(ws + WT_off);
    unsigned short* UT   = (unsigned short*)(ws + UT_off);
    void* xw             = (void*)(ws + xw_off);

    k_cast_x<<<16384, 256, 0, stream>>>(x, xT);
    dim3 tg(NG / 32, NI / 32);
    k_transpose_cast<<<tg, 256, 0, stream>>>(W, WT, NI, NG);
    k_transpose_cast<<<tg, 256, 0, stream>>>(U, UT, NH, NG);
    k_prep<<<65, 256, 0, stream>>>((uint4*)ws);
    if (xwf32) {
        k_gemm_xw<1><<<(NS * NB / 128) * (NG / 128), 256, 0, stream>>>(xT, WT, bias, xw);
        k_scan<1><<<GBLK, 256, 65536, stream>>>(UT, xw, hbuf, out, flags);
    } else {
        k_gemm_xw<0><<<(NS * NB / 128) * (NG / 128), 256, 0, stream>>>(xT, WT, bias, xw);
        k_scan<0><<<GBLK, 256, 65536, stream>>>(UT, xw, hbuf, out, flags);
    }
}

// Round 12
// 5842.467 us; speedup vs baseline: 1.4926x; 1.4186x over previous
//
#include <hip/hip_runtime.h>
#include <stdint.h>

#define DEVI __device__ __forceinline__

typedef __attribute__((ext_vector_type(4))) float f32x4;
typedef __attribute__((ext_vector_type(8))) short bf16x8;

constexpr int NB = 64;      // batch
constexpr int NS = 512;     // seq
constexpr int NI = 1024;    // input size
constexpr int NH = 1024;    // hidden size
constexpr int NG = 4096;    // 4*H
constexpr int GBLK = 128;   // step-kernel blocks (8 hidden units each)

DEVI unsigned short f2bf(float f) {
    unsigned u = __float_as_uint(f);
    unsigned r = (u + 0x7FFFu + ((u >> 16) & 1u)) >> 16;
    return (unsigned short)r;
}
DEVI float bf2f(unsigned short u) { return __uint_as_float(((unsigned)u) << 16); }

DEVI void gload_lds16(const void* g, void* l) {
    __builtin_amdgcn_global_load_lds(
        (const __attribute__((address_space(1))) unsigned int*)g,
        (__attribute__((address_space(3))) unsigned int*)l,
        16, 0, 0);
}

DEVI float fsigm(float x) { return 1.0f / (1.0f + __expf(-x)); }
DEVI float ftanh(float x) {
    x = fminf(fmaxf(x, -15.f), 15.f);
    float e = __expf(2.f * x);
    return (e - 1.f) / (e + 1.f);
}

#define MFMA16(a, b, c) __builtin_amdgcn_mfma_f32_16x16x32_bf16(a, b, c, 0, 0, 0)

// ---------------------------------------------------------------------------
// x[b][s][i] (f32) -> xT[s*64+b][i] (bf16)
__global__ void k_cast_x(const float* __restrict__ x, unsigned short* __restrict__ xT) {
    size_t e = ((size_t)blockIdx.x * blockDim.x + threadIdx.x) * 8;
    if (e >= (size_t)NB * NS * NI) return;
    unsigned i = (unsigned)(e & (NI - 1));
    unsigned s = (unsigned)((e >> 10) & (NS - 1));
    unsigned b = (unsigned)(e >> 19);
    const float4* p = (const float4*)(x + e);
    float4 v0 = p[0], v1 = p[1];
    bf16x8 w;
    w[0] = (short)f2bf(v0.x); w[1] = (short)f2bf(v0.y);
    w[2] = (short)f2bf(v0.z); w[3] = (short)f2bf(v0.w);
    w[4] = (short)f2bf(v1.x); w[5] = (short)f2bf(v1.y);
    w[6] = (short)f2bf(v1.z); w[7] = (short)f2bf(v1.w);
    *(bf16x8*)(xT + ((size_t)s * 64 + b) * NI + i) = w;
}

// src[rows][cols] (f32) -> dst[cols][rows] (bf16)
__global__ void k_transpose_cast(const float* __restrict__ src, unsigned short* __restrict__ dst,
                                 int rows, int cols) {
    __shared__ float tile[32][33];
    int c0 = blockIdx.x * 32;
    int r0 = blockIdx.y * 32;
    int tx = threadIdx.x & 31, ty = threadIdx.x >> 5;
    for (int rr = ty; rr < 32; rr += 8)
        tile[rr][tx] = src[(size_t)(r0 + rr) * cols + c0 + tx];
    __syncthreads();
    for (int rr = ty; rr < 32; rr += 8)
        dst[(size_t)(c0 + rr) * rows + r0 + tx] = f2bf(tile[tx][rr]);
}

// zero hbuf (256KB) + cstate (256KB)
__global__ void k_prep(uint4* ws0) {
    size_t idx = (size_t)blockIdx.x * blockDim.x + threadIdx.x;
    if (idx < (size_t)(2 * NB * NH * 2 + NB * NH * 4) / 16) ws0[idx] = make_uint4(0, 0, 0, 0);
}

// ---------------------------------------------------------------------------
// xW[s*64+b][g] = xT row . WT col + bias   (m97-structure 128x128x32 bf16 MFMA)
template <int XW_F32>
__global__ __launch_bounds__(256) void k_gemm_xw(
    const unsigned short* __restrict__ xT,   // [32768][1024]
    const unsigned short* __restrict__ WT,   // [4096][1024]  (= W^T)
    const float* __restrict__ bias,
    void* __restrict__ xw_out) {
    __shared__ unsigned short smA[128 * 32];
    __shared__ unsigned short smB[128 * 32];
    const int tid = threadIdx.x;
    const int w = tid >> 6, lane = tid & 63;
    const int l15 = lane & 15, l4 = lane >> 4;
    const int tm = blockIdx.x >> 5;   // 256 M tiles
    const int tn = blockIdx.x & 31;   // 32 N tiles
    const int rowbase = tm * 128, colbase = tn * 128;

    f32x4 zero = {0.f, 0.f, 0.f, 0.f};
    f32x4 acc[4][4];
#pragma unroll
    for (int mt = 0; mt < 4; ++mt)
#pragma unroll
        for (int nt = 0; nt < 4; ++nt) acc[mt][nt] = zero;

    for (int kk = 0; kk < 32; ++kk) {
        __syncthreads();
#pragma unroll
        for (int q = 0; q < 2; ++q) {
            int instr = w * 2 + q;
            int Lidx = instr * 64 + lane;        // 0..511
            int row = Lidx >> 2;                 // 0..127
            int koff = (Lidx & 3) * 16;          // bytes in 64B row
            gload_lds16((const char*)xT + ((size_t)(rowbase + row)) * 2048 + kk * 64 + koff,
                        (char*)smA + instr * 1024);
            gload_lds16((const char*)WT + ((size_t)(colbase + row)) * 2048 + kk * 64 + koff,
                        (char*)smB + instr * 1024);
        }
        __syncthreads();
        bf16x8 a[4], b[4];
        int mb = (w & 1) * 64, nb = (w >> 1) * 64;
#pragma unroll
        for (int mt = 0; mt < 4; ++mt)
            a[mt] = *(const bf16x8*)((const char*)smA + (mb + mt * 16 + l15) * 64 + l4 * 16);
#pragma unroll
        for (int nt = 0; nt < 4; ++nt)
            b[nt] = *(const bf16x8*)((const char*)smB + (nb + nt * 16 + l15) * 64 + l4 * 16);
#pragma unroll
        for (int mt = 0; mt < 4; ++mt)
#pragma unroll
            for (int nt = 0; nt < 4; ++nt)
                acc[mt][nt] = MFMA16(a[mt], b[nt], acc[mt][nt]);
    }
    int mbase = rowbase + (w & 1) * 64, nbase = colbase + (w >> 1) * 64;
#pragma unroll
    for (int nt = 0; nt < 4; ++nt) {
        int col = nbase + nt * 16 + l15;
        float bv = bias[col];
#pragma unroll
        for (int mt = 0; mt < 4; ++mt)
#pragma unroll
            for (int r = 0; r < 4; ++r) {
                int row = mbase + mt * 16 + l4 * 4 + r;
                float v = acc[mt][nt][r] + bv;
                if (XW_F32)
                    ((float*)xw_out)[(size_t)row * NG + col] = v;
                else
                    ((unsigned short*)xw_out)[(size_t)row * NG + col] = f2bf(v);
            }
    }
}

// ---------------------------------------------------------------------------
// One LSTM timestep. 128 blocks x 256 thr; block owns hidden units
// [8*blk, 8*blk+8) (gate cols {q*1024 + j}). Kernel boundary = the barrier:
// no atomics, no fences, no spins — h/c handoff via stream-ordered launches.
template <int XW_F32>
__global__ __launch_bounds__(256) void k_step(
    const unsigned short* __restrict__ UT,     // [4096][1024] (= U^T, bf16)
    const void* __restrict__ xw,               // [32768][4096]
    const unsigned short* __restrict__ hprev,  // [64][1024] bf16
    unsigned short* __restrict__ hnext,        // [64][1024] bf16
    float* __restrict__ cstate,                // [64][1024] f32
    float* __restrict__ out,                   // hidden_seq | h_t | c_t
    int t) {
    extern __shared__ char sm[];   // 64 KB U-slice
    const int tid = threadIdx.x, w = tid >> 6, lane = tid & 63;
    const int l15 = lane & 15, l4 = lane >> 4, jj = lane & 7;
    const int jbase = blockIdx.x * 8;

    // stage U-slice, swizzled: LDS(n, off) = UT(colg(n), off ^ ((n&7)<<4))
    for (int it = 0; it < 16; ++it) {
        int instr = it * 4 + w;
        int Lb = instr * 1024 + lane * 16;
        int n = Lb >> 11;                       // local col 0..31
        int off = Lb & 2047;
        int k2 = off ^ ((n & 7) << 4);
        int colg = (n >> 3) * 1024 + jbase + (n & 7);
        gload_lds16((const char*)UT + (size_t)colg * 2048 + k2, sm + instr * 1024);
    }

    const int batch0 = w * 16;
    const int q0 = l15 >> 3;
    const int colg0 = q0 * 1024 + jbase + jj;          // gates i/f
    const int colg1 = (2 + q0) * 1024 + jbase + jj;    // gates g/o
    const size_t HOFF = (size_t)NB * NS * NH;
    const size_t COFF = HOFF + (size_t)NB * NH;

    // seed accumulators with xw row t (C-in of MFMA)
    f32x4 acc0, acc1;
#pragma unroll
    for (int r = 0; r < 4; ++r) {
        int batch = batch0 + l4 * 4 + r;
        size_t rowoff = ((size_t)t * 64 + batch) * NG;
        if (XW_F32) {
            acc0[r] = ((const float*)xw)[rowoff + colg0];
            acc1[r] = ((const float*)xw)[rowoff + colg1];
        } else {
            acc0[r] = bf2f(((const unsigned short*)xw)[rowoff + colg0]);
            acc1[r] = bf2f(((const unsigned short*)xw)[rowoff + colg1]);
        }
    }

    // c state (lane pair reads same address — broadcast)
    float c[4];
#pragma unroll
    for (int r = 0; r < 4; ++r) {
        int batch = batch0 + l4 * 4 + r;
        c[r] = cstate[(size_t)batch * NH + jbase + jj];
    }

    // h fragments: plain vector loads (fresh via kernel-boundary coherence)
    const char* abase = (const char*)hprev + (size_t)(batch0 + l15) * 2048 + l4 * 16;
    bf16x8 hf[32];
#pragma unroll
    for (int kk = 0; kk < 32; ++kk)
        hf[kk] = *(const bf16x8*)(abase + (size_t)kk * 64);

    __syncthreads();   // drains gload_lds (vmcnt) before LDS reads

#pragma unroll
    for (int kk = 0; kk < 32; ++kk) {
        int k2 = kk * 64 + l4 * 16;
        bf16x8 b0 = *(const bf16x8*)(sm + (size_t)l15 * 2048 + (k2 ^ (jj << 4)));
        bf16x8 b1 = *(const bf16x8*)(sm + (size_t)(16 + l15) * 2048 + (k2 ^ (jj << 4)));
        acc0 = MFMA16(hf[kk], b0, acc0);
        acc1 = MFMA16(hf[kk], b1, acc1);
    }

    // elementwise: lanes l and l^8 pair up (i,f)/(g,o) for one hidden unit
    float hsv[4], csv[4];
#pragma unroll
    for (int r = 0; r < 4; ++r) {
        float p0 = acc0[r], p1 = acc1[r];
        float s0 = __shfl_xor(p0, 8);
        float s1 = __shfl_xor(p1, 8);
        bool hiLane = (lane & 8) != 0;
        float iv = hiLane ? s0 : p0;
        float fv = hiLane ? p0 : s0;
        float gv = hiLane ? s1 : p1;
        float ov = hiLane ? p1 : s1;
        float cn = fsigm(fv) * c[r] + fsigm(iv) * ftanh(gv);
        float h = fsigm(ov) * ftanh(cn);
        hsv[r] = h; csv[r] = cn;
    }
    if ((lane & 8) == 0) {
#pragma unroll
        for (int r = 0; r < 4; ++r) {
            int batch = batch0 + l4 * 4 + r;
            int j = jbase + jj;
            hnext[(size_t)batch * NH + j] = f2bf(hsv[r]);
            cstate[(size_t)batch * NH + j] = csv[r];
            out[((size_t)batch * NS + t) * NH + j] = hsv[r];
            if (t == NS - 1) {
                out[HOFF + (size_t)batch * NH + j] = hsv[r];
                out[COFF + (size_t)batch * NH + j] = csv[r];
            }
        }
    }
}

// ---------------------------------------------------------------------------
extern "C" void kernel_launch(void* const* d_in, const int* in_sizes, int n_in,
                              void* d_out, int out_size, void* d_ws, size_t ws_size,
                              hipStream_t stream) {
    const float* x    = (const float*)d_in[0];
    const float* W    = (const float*)d_in[1];
    const float* U    = (const float*)d_in[2];
    const float* bias = (const float*)d_in[3];
    float* out = (float*)d_out;
    char* ws = (char*)d_ws;

    const size_t hbuf_off = 0;                                        // 256KB
    const size_t c_off    = (size_t)2 * NB * NH * 2;                  // 256KB
    const size_t xT_off   = c_off + (size_t)NB * NH * 4;              // 524288
    const size_t WT_off   = xT_off + (size_t)NS * NB * NI * 2;        // +64MB
    const size_t UT_off   = WT_off + (size_t)NG * NI * 2;             // +8MB
    const size_t xw_off   = UT_off + (size_t)NG * NI * 2;             // +8MB
    const size_t need_f32 = xw_off + (size_t)NS * NB * NG * 4;        // ~592MB
    const bool xwf32 = (ws_size >= need_f32);

    unsigned short* hbuf = (unsigned short*)(ws + hbuf_off);  // [2][64][1024]
    float* cstate        = (float*)(ws + c_off);
    unsigned short* xT   = (unsigned short*)(ws + xT_off);
    unsigned short* WT   = (unsigned short*)(ws + WT_off);
    unsigned short* UT   = (unsigned short*)(ws + UT_off);
    void* xw             = (void*)(ws + xw_off);

    k_cast_x<<<16384, 256, 0, stream>>>(x, xT);
    dim3 tg(NG / 32, NI / 32);
    k_transpose_cast<<<tg, 256, 0, stream>>>(W, WT, NI, NG);
    k_transpose_cast<<<tg, 256, 0, stream>>>(U, UT, NH, NG);
    k_prep<<<128, 256, 0, stream>>>((uint4*)ws);

    if (xwf32) {
        k_gemm_xw<1><<<(NS * NB / 128) * (NG / 128), 256, 0, stream>>>(xT, WT, bias, xw);
        for (int t = 0; t < NS; ++t) {
            unsigned short* hp = hbuf + (size_t)(t & 1) * (NB * NH);
            unsigned short* hn = hbuf + (size_t)((t + 1) & 1) * (NB * NH);
            k_step<1><<<GBLK, 256, 65536, stream>>>(UT, xw, hp, hn, cstate, out, t);
        }
    } else {
        k_gemm_xw<0><<<(NS * NB / 128) * (NG / 128), 256, 0, stream>>>(xT, WT, bias, xw);
        for (int t = 0; t < NS; ++t) {
            unsigned short* hp = hbuf + (size_t)(t & 1) * (NB * NH);
            unsigned short* hn = hbuf + (size_t)((t + 1) & 1) * (NB * NH);
            k_step<0><<<GBLK, 256, 65536, stream>>>(UT, xw, hp, hn, cstate, out, t);
        }
    }
}